// Round 10
// baseline (379.743 us; speedup 1.0000x reference)
//
#include <hip/hip_runtime.h>
#include <math.h>
#include <stdint.h>

#define D_    2048
#define BLK   128    // 2 waves per block, one block per row
#define PBLK  256
#define KSEL  64
#define NBIN  512    // bin width 1/64 on |z|
#define B0    96     // gate: only |z| >= 1.5 enters the histogram (w/ fallback)
#define CAP   64     // max boundary candidates per select

typedef float v2f __attribute__((ext_vector_type(2)));

// same-wave LDS fence (used only for this wave's own scan-result slot)
#define FENCE() asm volatile("s_waitcnt lgkmcnt(0)" ::: "memory")

// ---------- exact-path helpers (must match np/XLA rounding) ----------
__device__ __forceinline__ float tanh_xla(float x) {
    const float kMax = 7.90531110763549805f;
    float xc = fminf(fmaxf(x, -kMax), kMax);
    float x2 = __fmul_rn(xc, xc);
    float p = -2.76076847742355e-16f;
    p = __fadd_rn(__fmul_rn(p, x2), 2.00018790482477e-13f);
    p = __fadd_rn(__fmul_rn(p, x2), -8.60467152213735e-11f);
    p = __fadd_rn(__fmul_rn(p, x2), 5.12229709037114e-08f);
    p = __fadd_rn(__fmul_rn(p, x2), 1.48572235717979e-05f);
    p = __fadd_rn(__fmul_rn(p, x2), 6.37261928875436e-04f);
    p = __fadd_rn(__fmul_rn(p, x2), 4.89352455891786e-03f);
    float num = __fmul_rn(xc, p);
    float q = 1.19825839466702e-06f;
    q = __fadd_rn(__fmul_rn(q, x2), 1.18534705686654e-04f);
    q = __fadd_rn(__fmul_rn(q, x2), 2.26843463243900e-03f);
    q = __fadd_rn(__fmul_rn(q, x2), 4.89352518554385e-03f);
    float r = __fdiv_rn(num, q);
    return (fabsf(x) < 0.0004f) ? x : r;
}

__device__ __forceinline__ float gelu_exact(float xx) {
    float a = __fmul_rn(0.044715f, xx);
    a = __fmul_rn(a, xx);
    a = __fmul_rn(a, xx);
    float inner = __fadd_rn(xx, a);
    float tg = tanh_xla(__fmul_rn(0.7978845608028654f, inner));
    return __fmul_rn(__fmul_rn(0.5f, xx), __fadd_rn(1.0f, tg));
}

// ---------- fast-path helpers (loose tolerance) ----------
__device__ __forceinline__ float tanh_fast(float y) {
    float e = __builtin_amdgcn_exp2f(y * 2.8853900817779268f);
    return 1.0f - 2.0f * __builtin_amdgcn_rcpf(1.0f + e);
}

__device__ __forceinline__ v2f gelu_fast2(v2f xx) {
    v2f x2 = xx * xx;
    v2f ax = xx * 0.044715f;
    v2f inner = __builtin_elementwise_fma(ax, x2, xx);
    v2f ea = inner * -2.3022269136469443f;   // -1.5957691 * log2(e)
    v2f ev; ev.x = __builtin_amdgcn_exp2f(ea.x);
    ev.y = __builtin_amdgcn_exp2f(ea.y);
    v2f dn = ev + 1.0f;
    v2f sg; sg.x = __builtin_amdgcn_rcpf(dn.x);
    sg.y = __builtin_amdgcn_rcpf(dn.y);
    return xx * sg;
}

// ---------- pre-kernel: denominators + ||dir||^2 + scalar params ----------
__global__ __launch_bounds__(PBLK) void prep_kernel(
    const float* __restrict__ m_in, const float* __restrict__ q_in,
    const float* __restrict__ m_out, const float* __restrict__ q_out,
    const float* __restrict__ dirv,
    const float* __restrict__ p_log_tau,
    const float* __restrict__ p_log_beta,
    const float* __restrict__ p_log_gamma,
    float* __restrict__ wsp)
{
    __shared__ float spart[4];
    const int t = threadIdx.x;
    const int c = blockIdx.x * PBLK + t;
    if (c < D_) {
        float mi = m_in[c];
        float vi = fmaxf(__fsub_rn(q_in[c], __fmul_rn(mi, mi)), 1e-4f);
        float di = __fadd_rn(__fsqrt_rn(vi), 1e-5f);
        wsp[c]        = di;                       // den_in
        wsp[D_ + c]   = __fdiv_rn(1.0f, di);      // inv_in
        float mo = m_out[c];
        float vo = fmaxf(__fsub_rn(q_out[c], __fmul_rn(mo, mo)), 1e-4f);
        float dd = __fadd_rn(__fsqrt_rn(vo), 1e-5f);
        wsp[2 * D_ + c] = dd;                     // den_out
        wsp[3 * D_ + c] = __fdiv_rn(1.0f, dd);    // inv_out
    }
    if (blockIdx.x == 0) {
        float acc = 0.f;
        #pragma unroll
        for (int k = 0; k < D_ / PBLK; ++k) {
            float v = dirv[t + k * PBLK];
            acc = fmaf(v, v, acc);
        }
        #pragma unroll
        for (int off = 32; off > 0; off >>= 1) acc += __shfl_xor(acc, off);
        if ((t & 63) == 0) spart[t >> 6] = acc;
        __syncthreads();
        if (t == 0) {
            wsp[4 * D_ + 0] = spart[0] + spart[1] + spart[2] + spart[3]; // ||dir||^2
            wsp[4 * D_ + 1] = expf(p_log_tau[0]);                        // tau
            wsp[4 * D_ + 2] = log1pf(expf(p_log_beta[0]));               // beta
            wsp[4 * D_ + 3] = log1pf(expf(p_log_gamma[0]));              // gamma
        }
    }
}

// packed-dual suffix scan + boundary find (IN=lo16, OUT=hi16) over 512 bins
__device__ __forceinline__ void scan_packed(
    const uint32_t* hist, uint32_t* scr, int lane)
{
    uint32_t h[8];
    *(uint4*)&h[0] = *(const uint4*)&hist[lane * 8 + 0];
    *(uint4*)&h[4] = *(const uint4*)&hist[lane * 8 + 4];
    uint32_t tot = 0;
    #pragma unroll
    for (int k = 0; k < 8; ++k) tot += h[k];   // u16 fields independent (<=2048)
    uint32_t S = tot;
    #pragma unroll
    for (int d = 1; d < 64; d <<= 1) {
        uint32_t o = __shfl_down(S, d, 64);
        S += (lane + d < 64) ? o : 0u;
    }
    uint32_t run = S - tot;   // packed suffix strictly after this lane's bins
    #pragma unroll
    for (int k = 7; k >= 0; --k) {
        uint32_t prev = run;
        run += h[k];
        uint32_t rl = run & 0xffffu, pl = prev & 0xffffu;
        if (rl >= (uint32_t)KSEL && pl < (uint32_t)KSEL) {
            scr[0] = (uint32_t)(lane * 8 + k);   // Bi
            scr[1] = pl;                          // Gi
        }
        uint32_t rh = run >> 16, ph = prev >> 16;
        if (rh >= (uint32_t)KSEL && ph < (uint32_t)KSEL) {
            scr[2] = (uint32_t)(lane * 8 + k);   // Bo
            scr[3] = ph;                          // Go
        }
    }
}

// ---------- main kernel: 2-wave block per row, minimal register state ----------
__global__ __launch_bounds__(BLK, 8) void gelu205_kernel(
    const float* __restrict__ x,
    const float* __restrict__ ema_mean,
    const float* __restrict__ ema_out_mean,
    const float* __restrict__ ema_out_dir,
    const float* __restrict__ wsp,
    float* __restrict__ out)
{
    __shared__ uint32_t hist[NBIN];          // packed: lo16=IN, hi16=OUT
    __shared__ uint32_t cbI[CAP], ciI[CAP], cfI[CAP];
    __shared__ uint32_t cbO[CAP], ciO[CAP], cfO[CAP];
    __shared__ uint32_t scrW[2][8];          // per-wave scan results
    __shared__ uint32_t snc[2];              // candidate counters (block-shared)
    __shared__ float sred[4];
    __shared__ float sgcos;

    const int t = threadIdx.x;
    const int lane = t & 63, wid = t >> 6;
    const int row = blockIdx.x;
    const float* xr = x + (size_t)row * D_;
    float* outr = out + (size_t)row * D_;

    const float dd_row = wsp[4 * D_ + 0];
    const float tau    = wsp[4 * D_ + 1];
    const float beta   = wsp[4 * D_ + 2];
    const float gamma  = wsp[4 * D_ + 3];

    // zero hist (4 dwords/thread) + counters + scan sentinels
    *(uint4*)&hist[t * 4] = make_uint4(0u, 0u, 0u, 0u);
    if (t < 2) snc[t] = 0u;
    if (lane < 8) scrW[wid][lane] = (lane == 0 || lane == 2) ? 0xffffffffu : 0u;

    // ---- pass 1: 16 elems/thread -> packed bins only, cosine partials ----
    uint32_t bp[16];                  // bin_in | bin_out<<16 (static index only)
    v2f acc_oo = {0.f, 0.f}, acc_od = {0.f, 0.f};

    #pragma unroll
    for (int g = 0; g < 4; ++g) {
        const int base = (g << 9) + (t << 2);
        float4 x4  = *(const float4*)(xr + base);
        float4 m4  = *(const float4*)(ema_mean + base);
        float4 i4  = *(const float4*)(wsp + D_ + base);       // inv_in
        float4 mo4 = *(const float4*)(ema_out_mean + base);
        float4 io4 = *(const float4*)(wsp + 3 * D_ + base);   // inv_out
        float4 d4  = *(const float4*)(ema_out_dir + base);
        const v2f* xp2  = (const v2f*)&x4;
        const v2f* mp2  = (const v2f*)&m4;
        const v2f* ip2  = (const v2f*)&i4;
        const v2f* mop2 = (const v2f*)&mo4;
        const v2f* iop2 = (const v2f*)&io4;
        const v2f* dp2  = (const v2f*)&d4;
        #pragma unroll
        for (int p = 0; p < 2; ++p) {
            const int j = g * 4 + p * 2;
            v2f xx = xp2[p];
            v2f o2 = gelu_fast2(xx);
            v2f zi2 = (xx - mp2[p]) * ip2[p];
            v2f zo2 = (o2 - mop2[p]) * iop2[p];
            v2f c511 = {511.0f, 511.0f};
            v2f bi = __builtin_elementwise_min(
                __builtin_elementwise_abs(zi2) * 64.0f, c511);
            v2f bo = __builtin_elementwise_min(
                __builtin_elementwise_abs(zo2) * 64.0f, c511);
            bp[j]     = (uint32_t)(int)bi.x | ((uint32_t)(int)bo.x << 16);
            bp[j + 1] = (uint32_t)(int)bi.y | ((uint32_t)(int)bo.y << 16);
            acc_oo = __builtin_elementwise_fma(o2, o2, acc_oo);
            acc_od = __builtin_elementwise_fma(o2, dp2[p], acc_od);
        }
        // cap load batching per group (VGPR pressure guard)
        asm volatile("" ::: "memory");
    }

    // ---- cosine gate: wave reduce, cross-wave combine by t0 ----
    float s_oo = acc_oo.x + acc_oo.y;
    float s_od = acc_od.x + acc_od.y;
    #pragma unroll
    for (int off = 32; off > 0; off >>= 1) {
        s_oo += __shfl_xor(s_oo, off);
        s_od += __shfl_xor(s_od, off);
    }
    if (lane == 0) {
        sred[wid * 2 + 0] = s_oo;
        sred[wid * 2 + 1] = s_od;
    }
    __syncthreads();                                   // B1

    // ---- gated packed histogram (IN:+1, OUT:+65536) ----
    #pragma unroll
    for (int j = 0; j < 16; ++j) {
        uint32_t bi = bp[j] & 0xffffu, bo = bp[j] >> 16;
        if (bi >= (uint32_t)B0) atomicAdd(&hist[bi], 1u);
        if (bo >= (uint32_t)B0) atomicAdd(&hist[bo], 65536u);
    }
    if (t == 0) {
        float oo = sred[0] + sred[2];
        float od = sred[1] + sred[3];
        float no = fmaxf(sqrtf(oo), 1e-12f);
        float nd = fmaxf(sqrtf(dd_row), 1e-12f);
        float cs = fminf(fmaxf(od / (no * nd), -1.0f), 1.0f);
        sgcos = expf(-tau * cs);
    }
    __syncthreads();                                   // B2

    // ---- redundant per-wave scan (no barrier needed after) ----
    scan_packed(hist, scrW[wid], lane);
    FENCE();
    int Bi = (int)scrW[wid][0], Bo = (int)scrW[wid][2];

    // uniform fallback: fewer than KSEL above the gate -> complete that hist
    if (Bi < 0 || Bo < 0) {
        #pragma unroll
        for (int j = 0; j < 16; ++j) {
            uint32_t bi = bp[j] & 0xffffu, bo = bp[j] >> 16;
            if (Bi < 0 && bi < (uint32_t)B0) atomicAdd(&hist[bi], 1u);
            if (Bo < 0 && bo < (uint32_t)B0) atomicAdd(&hist[bo], 65536u);
        }
        __syncthreads();
        scan_packed(hist, scrW[wid], lane);
        FENCE();
        Bi = (int)scrW[wid][0]; Bo = (int)scrW[wid][2];
    }

    // ---- above-boundary masks + boundary-candidate gather (exact values) ----
    uint32_t gtI = 0u, gtO = 0u;
    #pragma unroll
    for (int j = 0; j < 16; ++j) {
        const uint32_t bi = bp[j] & 0xffffu, bo = bp[j] >> 16;
        if ((int)bi > Bi) gtI |= 1u << j;
        if ((int)bo > Bo) gtO |= 1u << j;
        const int ch = ((j >> 2) << 9) + (t << 2) + (j & 3);
        if ((int)bi == Bi) {
            float xx = xr[ch];
            float ze = fabsf(__fdiv_rn(__fsub_rn(xx, ema_mean[ch]), wsp[ch]));
            uint32_t sl = atomicAdd(&snc[0], 1u);
            if (sl < (uint32_t)CAP) {
                cbI[sl] = __float_as_uint(ze);
                ciI[sl] = (uint32_t)ch;
            }
        }
        if ((int)bo == Bo) {
            float xx = xr[ch];
            float oe = gelu_exact(xx);
            float ze = fabsf(__fdiv_rn(__fsub_rn(oe, ema_out_mean[ch]),
                                       wsp[2 * D_ + ch]));
            uint32_t sl = atomicAdd(&snc[1], 1u);
            if (sl < (uint32_t)CAP) {
                cbO[sl] = __float_as_uint(ze);
                ciO[sl] = (uint32_t)ch;
            }
        }
    }
    __syncthreads();                                   // B3

    // ---- exact rank (value desc, index asc = jax tie rule) ----
    const int ncI = min((int)snc[0], CAP);
    const int ncO = min((int)snc[1], CAP);
    if (t < 64) {
        if (t < ncI) {
            const uint32_t needI = (uint32_t)(KSEL - (int)scrW[0][1]);
            uint32_t ui = cbI[t], di = ciI[t], r = 0;
            for (int jj = 0; jj < ncI; ++jj) {
                uint32_t uj = cbI[jj];
                r += (uj > ui || (uj == ui && ciI[jj] < di)) ? 1u : 0u;
            }
            cfI[t] = (r < needI) ? 1u : 0u;
        }
    } else {
        const int i = t - 64;
        if (i < ncO) {
            const uint32_t needO = (uint32_t)(KSEL - (int)scrW[1][3]);
            uint32_t ui = cbO[i], di = ciO[i], r = 0;
            for (int jj = 0; jj < ncO; ++jj) {
                uint32_t uj = cbO[jj];
                r += (uj > ui || (uj == ui && ciO[jj] < di)) ? 1u : 0u;
            }
            cfO[i] = (r < needO) ? 1u : 0u;
        }
    }
    __syncthreads();                                   // B4

    // ---- boundary-winner bitmasks for this thread's 16 elements ----
    uint32_t bmI = 0u, bmO = 0u;
    for (int i = 0; i < ncI; ++i) {
        uint32_t ch = ciI[i];
        if (((ch >> 2) & 127u) == (uint32_t)t && cfI[i])
            bmI |= 1u << (((ch >> 9) << 2) | (ch & 3u));
    }
    for (int i = 0; i < ncO; ++i) {
        uint32_t ch = ciO[i];
        if (((ch >> 2) & 127u) == (uint32_t)t && cfO[i])
            bmO |= 1u << (((ch >> 9) << 2) | (ch & 3u));
    }
    const uint32_t selm = (gtI | bmI) & (gtO | bmO);
    const float gcos = sgcos;

    // ---- epilogue: recompute o (fast), lazy gate, write ----
    #pragma unroll
    for (int g = 0; g < 4; ++g) {
        const int base = (g << 9) + (t << 2);
        float4 x4 = *(const float4*)(xr + base);
        v2f o2a = gelu_fast2(((const v2f*)&x4)[0]);
        v2f o2b = gelu_fast2(((const v2f*)&x4)[1]);
        const float o4[4] = {o2a.x, o2a.y, o2b.x, o2b.y};
        float4 r4;
        float* rp = (float*)&r4;
        #pragma unroll
        for (int e = 0; e < 4; ++e) {
            const int j = g * 4 + e;
            float gate = 1.0f;
            if ((selm >> j) & 1u) {
                const int ch = base + e;
                float xx = ((const float*)&x4)[e];
                float zi = (xx - ema_mean[ch]) * wsp[D_ + ch];
                float th = tanh_fast(gamma * zi);
                gate = fminf(fmaxf(fmaf(beta, th, 1.0f), 0.1f), 8.0f);
            }
            rp[e] = o4[e] * gate * gcos;
        }
        *(float4*)(outr + base) = r4;
    }
}

extern "C" void kernel_launch(void* const* d_in, const int* in_sizes, int n_in,
                              void* d_out, int out_size, void* d_ws, size_t ws_size,
                              hipStream_t stream) {
    const float* x            = (const float*)d_in[0];
    const float* p_log_tau    = (const float*)d_in[2];
    const float* p_log_beta   = (const float*)d_in[3];
    const float* p_log_gamma  = (const float*)d_in[4];
    const float* ema_mean     = (const float*)d_in[5];
    const float* ema_sq       = (const float*)d_in[6];
    const float* ema_out_mean = (const float*)d_in[7];
    const float* ema_out_sq   = (const float*)d_in[8];
    const float* ema_out_dir  = (const float*)d_in[9];
    float* wsp = (float*)d_ws;
    const int rows = in_sizes[0] / D_;

    prep_kernel<<<(D_ + PBLK - 1) / PBLK, PBLK, 0, stream>>>(
        ema_mean, ema_sq, ema_out_mean, ema_out_sq, ema_out_dir,
        p_log_tau, p_log_beta, p_log_gamma, wsp);
    gelu205_kernel<<<rows, BLK, 0, stream>>>(
        x, ema_mean, ema_out_mean, ema_out_dir, wsp,
        (float*)d_out);
}

// Round 11
// 86.233 us; speedup vs baseline: 4.4037x; 4.4037x over previous
//
#include <hip/hip_runtime.h>
#include <math.h>
#include <stdint.h>

#define D_    2048
#define BLK   256
#define KSEL  64
#define NBIN  512    // bin width 1/64 on |z|
#define B0    96     // gate: only |z| >= 1.5 enters the histogram (w/ fallback)
#define CAP   128    // max boundary candidates per select

typedef float v2f __attribute__((ext_vector_type(2)));

// ---------- exact-path helpers (must match np/XLA rounding) ----------
__device__ __forceinline__ float tanh_xla(float x) {
    const float kMax = 7.90531110763549805f;
    float xc = fminf(fmaxf(x, -kMax), kMax);
    float x2 = __fmul_rn(xc, xc);
    float p = -2.76076847742355e-16f;
    p = __fadd_rn(__fmul_rn(p, x2), 2.00018790482477e-13f);
    p = __fadd_rn(__fmul_rn(p, x2), -8.60467152213735e-11f);
    p = __fadd_rn(__fmul_rn(p, x2), 5.12229709037114e-08f);
    p = __fadd_rn(__fmul_rn(p, x2), 1.48572235717979e-05f);
    p = __fadd_rn(__fmul_rn(p, x2), 6.37261928875436e-04f);
    p = __fadd_rn(__fmul_rn(p, x2), 4.89352455891786e-03f);
    float num = __fmul_rn(xc, p);
    float q = 1.19825839466702e-06f;
    q = __fadd_rn(__fmul_rn(q, x2), 1.18534705686654e-04f);
    q = __fadd_rn(__fmul_rn(q, x2), 2.26843463243900e-03f);
    q = __fadd_rn(__fmul_rn(q, x2), 4.89352518554385e-03f);
    float r = __fdiv_rn(num, q);
    return (fabsf(x) < 0.0004f) ? x : r;
}

__device__ __forceinline__ float gelu_exact(float xx) {
    float a = __fmul_rn(0.044715f, xx);
    a = __fmul_rn(a, xx);
    a = __fmul_rn(a, xx);
    float inner = __fadd_rn(xx, a);
    float tg = tanh_xla(__fmul_rn(0.7978845608028654f, inner));
    return __fmul_rn(__fmul_rn(0.5f, xx), __fadd_rn(1.0f, tg));
}

// ---------- fast-path helpers (loose tolerance) ----------
__device__ __forceinline__ float tanh_fast(float y) {
    float e = __builtin_amdgcn_exp2f(y * 2.8853900817779268f);
    return 1.0f - 2.0f * __builtin_amdgcn_rcpf(1.0f + e);
}

// ---------- pre-kernel: denominators + ||dir||^2 + scalar params ----------
__global__ __launch_bounds__(BLK) void prep_kernel(
    const float* __restrict__ m_in, const float* __restrict__ q_in,
    const float* __restrict__ m_out, const float* __restrict__ q_out,
    const float* __restrict__ dirv,
    const float* __restrict__ p_log_tau,
    const float* __restrict__ p_log_beta,
    const float* __restrict__ p_log_gamma,
    float* __restrict__ wsp)
{
    __shared__ float spart[4];
    const int t = threadIdx.x;
    const int c = blockIdx.x * BLK + t;
    if (c < D_) {
        float mi = m_in[c];
        float vi = fmaxf(__fsub_rn(q_in[c], __fmul_rn(mi, mi)), 1e-4f);
        float di = __fadd_rn(__fsqrt_rn(vi), 1e-5f);
        wsp[c]        = di;                       // den_in
        wsp[D_ + c]   = __fdiv_rn(1.0f, di);      // inv_in
        float mo = m_out[c];
        float vo = fmaxf(__fsub_rn(q_out[c], __fmul_rn(mo, mo)), 1e-4f);
        float dd = __fadd_rn(__fsqrt_rn(vo), 1e-5f);
        wsp[2 * D_ + c] = dd;                     // den_out
        wsp[3 * D_ + c] = __fdiv_rn(1.0f, dd);    // inv_out
    }
    if (blockIdx.x == 0) {
        float acc = 0.f;
        #pragma unroll
        for (int k = 0; k < D_ / BLK; ++k) {
            float v = dirv[t + k * BLK];
            acc = fmaf(v, v, acc);
        }
        #pragma unroll
        for (int off = 32; off > 0; off >>= 1) acc += __shfl_xor(acc, off);
        if ((t & 63) == 0) spart[t >> 6] = acc;
        __syncthreads();
        if (t == 0) {
            wsp[4 * D_ + 0] = spart[0] + spart[1] + spart[2] + spart[3]; // ||dir||^2
            wsp[4 * D_ + 1] = expf(p_log_tau[0]);                        // tau
            wsp[4 * D_ + 2] = log1pf(expf(p_log_beta[0]));               // beta
            wsp[4 * D_ + 3] = log1pf(expf(p_log_gamma[0]));              // gamma
        }
    }
}

// suffix scan + boundary find over both 512-bin hists (waves 0 and 1)
__device__ __forceinline__ void scan_find(
    const uint32_t* hist, int wid, int lane,
    int* sBi, int* sGi, int* sBo, int* sGo)
{
    if (wid < 2) {
        const uint32_t* hp = hist + wid * NBIN;
        uint32_t h[8];
        *(uint4*)&h[0] = *(const uint4*)&hp[lane * 8 + 0];
        *(uint4*)&h[4] = *(const uint4*)&hp[lane * 8 + 4];
        uint32_t tot = 0;
        #pragma unroll
        for (int k = 0; k < 8; ++k) tot += h[k];
        uint32_t S = tot;
        #pragma unroll
        for (int d2 = 1; d2 < 64; d2 <<= 1) {
            uint32_t o = __shfl_down(S, d2, 64);
            S += (lane + d2 < 64) ? o : 0u;
        }
        uint32_t run = S - tot;   // suffix strictly after this lane's bins
        #pragma unroll
        for (int k = 7; k >= 0; --k) {
            uint32_t prev = run;
            run += h[k];
            if (run >= (uint32_t)KSEL && prev < (uint32_t)KSEL) {
                if (wid == 0) { *sBi = lane * 8 + k; *sGi = (int)prev; }
                else          { *sBo = lane * 8 + k; *sGo = (int)prev; }
            }
        }
    }
}

// ---------- main kernel: one block per row (r5 structure, owner-side rank) ----------
__global__ __launch_bounds__(BLK) void gelu205_kernel(
    const float* __restrict__ x,
    const float* __restrict__ ema_mean,
    const float* __restrict__ ema_out_mean,
    const float* __restrict__ ema_out_dir,
    const float* __restrict__ wsp,
    float* __restrict__ out)
{
    __shared__ uint32_t hist[2 * NBIN];          // [0..511]=IN, [512..]=OUT
    __shared__ uint32_t cbI[CAP], ciI[CAP];
    __shared__ uint32_t cbO[CAP], ciO[CAP];
    __shared__ float sred[8];
    __shared__ float sgcos;
    __shared__ int sBi, sGi, sNCi, sBo, sGo, sNCo;

    const int t = threadIdx.x;
    const int row = blockIdx.x;
    const float* xr = x + (size_t)row * D_;
    float* outr = out + (size_t)row * D_;

    const float* den_in  = wsp;
    const float* inv_in  = wsp + D_;
    const float* den_out = wsp + 2 * D_;
    const float* inv_out = wsp + 3 * D_;
    const float dd_row = wsp[4 * D_ + 0];
    const float tau    = wsp[4 * D_ + 1];
    const float beta   = wsp[4 * D_ + 2];
    const float gamma  = wsp[4 * D_ + 3];

    float ov[8], zif[8];
    int bin_in[8], bin_out[8];
    v2f acc_oo = {0.f, 0.f}, acc_od = {0.f, 0.f};

    #pragma unroll
    for (int g = 0; g < 2; ++g) {
        const int base = (g << 10) + (t << 2);
        float4 x4  = *(const float4*)(xr + base);
        float4 m4  = *(const float4*)(ema_mean + base);
        float4 i4  = *(const float4*)(inv_in + base);
        float4 mo4 = *(const float4*)(ema_out_mean + base);
        float4 io4 = *(const float4*)(inv_out + base);
        float4 d4  = *(const float4*)(ema_out_dir + base);
        const v2f* xp2  = (const v2f*)&x4;
        const v2f* mp2  = (const v2f*)&m4;
        const v2f* ip2  = (const v2f*)&i4;
        const v2f* mop2 = (const v2f*)&mo4;
        const v2f* iop2 = (const v2f*)&io4;
        const v2f* dp2  = (const v2f*)&d4;
        #pragma unroll
        for (int p = 0; p < 2; ++p) {
            const int j = g * 4 + p * 2;
            v2f xx = xp2[p];
            // fast gelu: x * sigmoid(1.5957691*(x+0.044715x^3)) via exp2
            v2f x2 = xx * xx;
            v2f ax = xx * 0.044715f;
            v2f inner = __builtin_elementwise_fma(ax, x2, xx);
            v2f ea = inner * -2.3022269136469443f;
            v2f ev; ev.x = __builtin_amdgcn_exp2f(ea.x);
            ev.y = __builtin_amdgcn_exp2f(ea.y);
            v2f dn = ev + 1.0f;
            v2f sgm; sgm.x = __builtin_amdgcn_rcpf(dn.x);
            sgm.y = __builtin_amdgcn_rcpf(dn.y);
            v2f o2 = xx * sgm;
            ov[j] = o2.x; ov[j + 1] = o2.y;
            v2f zi2 = (xx - mp2[p]) * ip2[p];
            zif[j] = zi2.x; zif[j + 1] = zi2.y;
            bin_in[j]     = (int)fminf(fabsf(zi2.x) * 64.0f, 511.0f);
            bin_in[j + 1] = (int)fminf(fabsf(zi2.y) * 64.0f, 511.0f);
            v2f zo2 = (o2 - mop2[p]) * iop2[p];
            bin_out[j]     = (int)fminf(fabsf(zo2.x) * 64.0f, 511.0f);
            bin_out[j + 1] = (int)fminf(fabsf(zo2.y) * 64.0f, 511.0f);
            acc_oo = __builtin_elementwise_fma(o2, o2, acc_oo);
            acc_od = __builtin_elementwise_fma(o2, dp2[p], acc_od);
        }
    }
    float s_oo = acc_oo.x + acc_oo.y;
    float s_od = acc_od.x + acc_od.y;

    // wave reduce for cosine gate
    #pragma unroll
    for (int off = 32; off > 0; off >>= 1) {
        s_oo += __shfl_xor(s_oo, off);
        s_od += __shfl_xor(s_od, off);
    }
    const int wid = t >> 6, lane = t & 63;
    if (lane == 0) {
        sred[wid * 2 + 0] = s_oo;
        sred[wid * 2 + 1] = s_od;
    }

    // zero hists (one uint4/thread) + init flags
    *(uint4*)&hist[t * 4] = make_uint4(0u, 0u, 0u, 0u);
    if (t == 0) { sNCi = 0; sNCo = 0; sBi = -1; sBo = -1; }
    __syncthreads();                                   // B1

    // gated histogram build: only bins >= B0 can matter (fallback below)
    #pragma unroll
    for (int j = 0; j < 8; ++j) {
        if (bin_in[j] >= B0)  atomicAdd(&hist[bin_in[j]], 1u);
        if (bin_out[j] >= B0) atomicAdd(&hist[NBIN + bin_out[j]], 1u);
    }
    if (t == 0) {
        float oo = sred[0] + sred[2] + sred[4] + sred[6];
        float od = sred[1] + sred[3] + sred[5] + sred[7];
        float no = fmaxf(sqrtf(oo), 1e-12f);
        float nd = fmaxf(sqrtf(dd_row), 1e-12f);
        float cs = fminf(fmaxf(od / (no * nd), -1.0f), 1.0f);
        sgcos = expf(-tau * cs);
    }
    __syncthreads();                                   // B2

    scan_find(hist, wid, lane, &sBi, &sGi, &sBo, &sGo);
    __syncthreads();                                   // B3

    int Bi = sBi, Bo = sBo;
    // uniform fallback: fewer than KSEL elements above the gate
    if (Bi < 0 || Bo < 0) {
        #pragma unroll
        for (int j = 0; j < 8; ++j) {
            if (bin_in[j] < B0)  atomicAdd(&hist[bin_in[j]], 1u);
            if (bin_out[j] < B0) atomicAdd(&hist[NBIN + bin_out[j]], 1u);
        }
        __syncthreads();
        scan_find(hist, wid, lane, &sBi, &sGi, &sBo, &sGo);
        __syncthreads();
        Bi = sBi; Bo = sBo;
    }

    // gather boundary candidates; owners push EXACT values (no slot tracking)
    #pragma unroll
    for (int j = 0; j < 8; ++j) {
        const int ch = ((j >> 2) << 10) + (t << 2) + (j & 3);
        if (bin_in[j] == Bi) {
            float xx = xr[ch];
            float ze = fabsf(__fdiv_rn(__fsub_rn(xx, ema_mean[ch]), den_in[ch]));
            int sl = atomicAdd(&sNCi, 1);
            if (sl < CAP) {
                cbI[sl] = __float_as_uint(ze);
                ciI[sl] = (uint32_t)ch;
            }
        }
        if (bin_out[j] == Bo) {
            float xx = xr[ch];
            float oe = gelu_exact(xx);
            float ze = fabsf(__fdiv_rn(__fsub_rn(oe, ema_out_mean[ch]), den_out[ch]));
            int sl = atomicAdd(&sNCo, 1);
            if (sl < CAP) {
                cbO[sl] = __float_as_uint(ze);
                ciO[sl] = (uint32_t)ch;
            }
        }
    }
    __syncthreads();                                   // B4 (candidates visible)

    const int nci = min(sNCi, CAP), nco = min(sNCo, CAP);
    const uint32_t needI = (uint32_t)(KSEL - sGi);
    const uint32_t needO = (uint32_t)(KSEL - sGo);

    // epilogue: owner-side rank for boundary elems, lazy gate, write
    const float gcos = sgcos;
    #pragma unroll
    for (int g = 0; g < 2; ++g) {
        float4 r4;
        float* rp = (float*)&r4;
        #pragma unroll
        for (int l = 0; l < 4; ++l) {
            const int j = g * 4 + l;
            const int ch = (g << 10) + (t << 2) + l;
            bool selI = bin_in[j] > Bi;
            if (bin_in[j] == Bi) {
                float xx = xr[ch];
                float ze = fabsf(__fdiv_rn(__fsub_rn(xx, ema_mean[ch]), den_in[ch]));
                uint32_t ui = __float_as_uint(ze), r = 0;
                for (int jj = 0; jj < nci; ++jj) {
                    uint32_t uj = cbI[jj];
                    r += (uj > ui || (uj == ui && ciI[jj] < (uint32_t)ch)) ? 1u : 0u;
                }
                selI = (r < needI);
            }
            bool selO = bin_out[j] > Bo;
            if (bin_out[j] == Bo) {
                float xx = xr[ch];
                float oe = gelu_exact(xx);
                float ze = fabsf(__fdiv_rn(__fsub_rn(oe, ema_out_mean[ch]), den_out[ch]));
                uint32_t ui = __float_as_uint(ze), r = 0;
                for (int jj = 0; jj < nco; ++jj) {
                    uint32_t uj = cbO[jj];
                    r += (uj > ui || (uj == ui && ciO[jj] < (uint32_t)ch)) ? 1u : 0u;
                }
                selO = (r < needO);
            }
            float gate = 1.0f;
            if (selI && selO) {
                float th = tanh_fast(gamma * zif[j]);
                gate = fminf(fmaxf(fmaf(beta, th, 1.0f), 0.1f), 8.0f);
            }
            rp[l] = ov[j] * gate * gcos;
        }
        *(float4*)(outr + (g << 10) + (t << 2)) = r4;
    }
}

extern "C" void kernel_launch(void* const* d_in, const int* in_sizes, int n_in,
                              void* d_out, int out_size, void* d_ws, size_t ws_size,
                              hipStream_t stream) {
    const float* x            = (const float*)d_in[0];
    const float* p_log_tau    = (const float*)d_in[2];
    const float* p_log_beta   = (const float*)d_in[3];
    const float* p_log_gamma  = (const float*)d_in[4];
    const float* ema_mean     = (const float*)d_in[5];
    const float* ema_sq       = (const float*)d_in[6];
    const float* ema_out_mean = (const float*)d_in[7];
    const float* ema_out_sq   = (const float*)d_in[8];
    const float* ema_out_dir  = (const float*)d_in[9];
    float* wsp = (float*)d_ws;
    const int rows = in_sizes[0] / D_;

    prep_kernel<<<(D_ + BLK - 1) / BLK, BLK, 0, stream>>>(
        ema_mean, ema_sq, ema_out_mean, ema_out_sq, ema_out_dir,
        p_log_tau, p_log_beta, p_log_gamma, wsp);
    gelu205_kernel<<<rows, BLK, 0, stream>>>(
        x, ema_mean, ema_out_mean, ema_out_dir, wsp,
        (float*)d_out);
}

// Round 12
// 75.204 us; speedup vs baseline: 5.0495x; 1.1467x over previous
//
#include <hip/hip_runtime.h>
#include <math.h>
#include <stdint.h>

#define D_    2048
#define BLK   256
#define KSEL  64
#define NBIN  512    // bin width 1/64 on |z|
#define B0    96     // gate: only |z| >= 1.5 enters the histogram (w/ fallback)
#define CAP   128    // max boundary candidates per select

typedef float v2f __attribute__((ext_vector_type(2)));

// ---------- exact-path helpers (must match np/XLA rounding) ----------
__device__ __forceinline__ float tanh_xla(float x) {
    const float kMax = 7.90531110763549805f;
    float xc = fminf(fmaxf(x, -kMax), kMax);
    float x2 = __fmul_rn(xc, xc);
    float p = -2.76076847742355e-16f;
    p = __fadd_rn(__fmul_rn(p, x2), 2.00018790482477e-13f);
    p = __fadd_rn(__fmul_rn(p, x2), -8.60467152213735e-11f);
    p = __fadd_rn(__fmul_rn(p, x2), 5.12229709037114e-08f);
    p = __fadd_rn(__fmul_rn(p, x2), 1.48572235717979e-05f);
    p = __fadd_rn(__fmul_rn(p, x2), 6.37261928875436e-04f);
    p = __fadd_rn(__fmul_rn(p, x2), 4.89352455891786e-03f);
    float num = __fmul_rn(xc, p);
    float q = 1.19825839466702e-06f;
    q = __fadd_rn(__fmul_rn(q, x2), 1.18534705686654e-04f);
    q = __fadd_rn(__fmul_rn(q, x2), 2.26843463243900e-03f);
    q = __fadd_rn(__fmul_rn(q, x2), 4.89352518554385e-03f);
    float r = __fdiv_rn(num, q);
    return (fabsf(x) < 0.0004f) ? x : r;
}

__device__ __forceinline__ float gelu_exact(float xx) {
    float a = __fmul_rn(0.044715f, xx);
    a = __fmul_rn(a, xx);
    a = __fmul_rn(a, xx);
    float inner = __fadd_rn(xx, a);
    float tg = tanh_xla(__fmul_rn(0.7978845608028654f, inner));
    return __fmul_rn(__fmul_rn(0.5f, xx), __fadd_rn(1.0f, tg));
}

// ---------- fast-path helpers (loose tolerance) ----------
__device__ __forceinline__ float tanh_fast(float y) {
    // tanh(y) = 1 - 2/(1+exp(2y));  exp(2y) = exp2(y * 2*log2(e))
    float e = __builtin_amdgcn_exp2f(y * 2.8853900817779268f);
    return 1.0f - 2.0f * __builtin_amdgcn_rcpf(1.0f + e);
}

// ---------- pre-kernel: denominators + ||dir||^2 + scalar params ----------
__global__ __launch_bounds__(BLK) void prep_kernel(
    const float* __restrict__ m_in, const float* __restrict__ q_in,
    const float* __restrict__ m_out, const float* __restrict__ q_out,
    const float* __restrict__ dirv,
    const float* __restrict__ p_log_tau,
    const float* __restrict__ p_log_beta,
    const float* __restrict__ p_log_gamma,
    float* __restrict__ wsp)
{
    __shared__ float spart[4];
    const int t = threadIdx.x;
    const int c = blockIdx.x * BLK + t;
    if (c < D_) {
        float mi = m_in[c];
        float vi = fmaxf(__fsub_rn(q_in[c], __fmul_rn(mi, mi)), 1e-4f);
        float di = __fadd_rn(__fsqrt_rn(vi), 1e-5f);
        wsp[c]        = di;                       // den_in
        wsp[D_ + c]   = __fdiv_rn(1.0f, di);      // inv_in
        float mo = m_out[c];
        float vo = fmaxf(__fsub_rn(q_out[c], __fmul_rn(mo, mo)), 1e-4f);
        float dd = __fadd_rn(__fsqrt_rn(vo), 1e-5f);
        wsp[2 * D_ + c] = dd;                     // den_out
        wsp[3 * D_ + c] = __fdiv_rn(1.0f, dd);    // inv_out
    }
    if (blockIdx.x == 0) {
        float acc = 0.f;
        #pragma unroll
        for (int k = 0; k < D_ / BLK; ++k) {
            float v = dirv[t + k * BLK];
            acc = fmaf(v, v, acc);
        }
        #pragma unroll
        for (int off = 32; off > 0; off >>= 1) acc += __shfl_xor(acc, off);
        if ((t & 63) == 0) spart[t >> 6] = acc;
        __syncthreads();
        if (t == 0) {
            wsp[4 * D_ + 0] = spart[0] + spart[1] + spart[2] + spart[3]; // ||dir||^2
            wsp[4 * D_ + 1] = expf(p_log_tau[0]);                        // tau
            wsp[4 * D_ + 2] = log1pf(expf(p_log_beta[0]));               // beta
            wsp[4 * D_ + 3] = log1pf(expf(p_log_gamma[0]));              // gamma
        }
    }
}

// suffix scan + boundary find over both 512-bin hists (waves 0 and 1)
__device__ __forceinline__ void scan_find(
    const uint32_t* hist, int wid, int lane,
    int* sBi, int* sGi, int* sBo, int* sGo)
{
    if (wid < 2) {
        const uint32_t* hp = hist + wid * NBIN;
        uint32_t h[8];
        *(uint4*)&h[0] = *(const uint4*)&hp[lane * 8 + 0];
        *(uint4*)&h[4] = *(const uint4*)&hp[lane * 8 + 4];
        uint32_t tot = 0;
        #pragma unroll
        for (int k = 0; k < 8; ++k) tot += h[k];
        uint32_t S = tot;
        #pragma unroll
        for (int d2 = 1; d2 < 64; d2 <<= 1) {
            uint32_t o = __shfl_down(S, d2, 64);
            S += (lane + d2 < 64) ? o : 0u;
        }
        uint32_t run = S - tot;   // suffix strictly after this lane's bins
        #pragma unroll
        for (int k = 7; k >= 0; --k) {
            uint32_t prev = run;
            run += h[k];
            if (run >= (uint32_t)KSEL && prev < (uint32_t)KSEL) {
                if (wid == 0) { *sBi = lane * 8 + k; *sGi = (int)prev; }
                else          { *sBo = lane * 8 + k; *sGo = (int)prev; }
            }
        }
    }
}

// ---------- main kernel: one block per row ----------
__global__ __launch_bounds__(BLK) void gelu205_kernel(
    const float* __restrict__ x,
    const float* __restrict__ ema_mean,
    const float* __restrict__ ema_out_mean,
    const float* __restrict__ ema_out_dir,
    const float* __restrict__ wsp,
    float* __restrict__ out)
{
    __shared__ uint32_t hist[2 * NBIN];          // [0..511]=IN, [512..]=OUT
    __shared__ uint32_t cbI[CAP], ciI[CAP], cfI[CAP];
    __shared__ uint32_t cbO[CAP], ciO[CAP], cfO[CAP];
    __shared__ float sred[8];
    __shared__ float sgcos;
    __shared__ int sBi, sGi, sNCi, sBo, sGo, sNCo;

    const int t = threadIdx.x;
    const int row = blockIdx.x;
    const float* xr = x + (size_t)row * D_;
    float* outr = out + (size_t)row * D_;

    const float* den_in  = wsp;
    const float* inv_in  = wsp + D_;
    const float* den_out = wsp + 2 * D_;
    const float* inv_out = wsp + 3 * D_;
    const float dd_row = wsp[4 * D_ + 0];
    const float tau    = wsp[4 * D_ + 1];
    const float beta   = wsp[4 * D_ + 2];
    const float gamma  = wsp[4 * D_ + 3];

    float ov[8], zif[8];
    int bin_in[8], bin_out[8];
    v2f acc_oo = {0.f, 0.f}, acc_od = {0.f, 0.f};

    #pragma unroll
    for (int g = 0; g < 2; ++g) {
        const int base = (g << 10) + t * 4;
        float4 x4  = *(const float4*)(xr + base);
        float4 m4  = *(const float4*)(ema_mean + base);
        float4 i4  = *(const float4*)(inv_in + base);
        float4 mo4 = *(const float4*)(ema_out_mean + base);
        float4 io4 = *(const float4*)(inv_out + base);
        float4 d4  = *(const float4*)(ema_out_dir + base);
        const v2f* xp2  = (const v2f*)&x4;
        const v2f* mp2  = (const v2f*)&m4;
        const v2f* ip2  = (const v2f*)&i4;
        const v2f* mop2 = (const v2f*)&mo4;
        const v2f* iop2 = (const v2f*)&io4;
        const v2f* dp2  = (const v2f*)&d4;
        #pragma unroll
        for (int p = 0; p < 2; ++p) {
            const int j = g * 4 + p * 2;
            v2f xx = xp2[p];
            // fast gelu: x * sigmoid(1.5957691 * (x + 0.044715 x^3))
            // exp(-1.5957691*i) = exp2(i * -1.5957691*log2(e))
            v2f x2 = xx * xx;
            v2f ax = xx * 0.044715f;
            v2f inner = __builtin_elementwise_fma(ax, x2, xx);
            v2f ea = inner * -2.3022269136469443f;
            v2f ev; ev.x = __builtin_amdgcn_exp2f(ea.x);
            ev.y = __builtin_amdgcn_exp2f(ea.y);
            v2f dn = ev + 1.0f;
            v2f sgm; sgm.x = __builtin_amdgcn_rcpf(dn.x);
            sgm.y = __builtin_amdgcn_rcpf(dn.y);
            v2f o2 = xx * sgm;
            ov[j] = o2.x; ov[j + 1] = o2.y;
            v2f zi2 = (xx - mp2[p]) * ip2[p];
            zif[j] = zi2.x; zif[j + 1] = zi2.y;
            bin_in[j]     = (int)fminf(fabsf(zi2.x) * 64.0f, 511.0f);
            bin_in[j + 1] = (int)fminf(fabsf(zi2.y) * 64.0f, 511.0f);
            v2f zo2 = (o2 - mop2[p]) * iop2[p];
            bin_out[j]     = (int)fminf(fabsf(zo2.x) * 64.0f, 511.0f);
            bin_out[j + 1] = (int)fminf(fabsf(zo2.y) * 64.0f, 511.0f);
            acc_oo = __builtin_elementwise_fma(o2, o2, acc_oo);
            acc_od = __builtin_elementwise_fma(o2, dp2[p], acc_od);
        }
    }
    float s_oo = acc_oo.x + acc_oo.y;
    float s_od = acc_od.x + acc_od.y;

    // wave reduce for cosine gate
    #pragma unroll
    for (int off = 32; off > 0; off >>= 1) {
        s_oo += __shfl_xor(s_oo, off);
        s_od += __shfl_xor(s_od, off);
    }
    const int wid = t >> 6, lane = t & 63;
    if (lane == 0) {
        sred[wid * 2 + 0] = s_oo;
        sred[wid * 2 + 1] = s_od;
    }

    // zero hists (one uint4/thread) + init flags
    *(uint4*)&hist[t * 4] = make_uint4(0u, 0u, 0u, 0u);
    if (t == 0) { sNCi = 0; sNCo = 0; sBi = -1; sBo = -1; }
    __syncthreads();                                   // B1

    // gated histogram build: only bins >= B0 can matter (fallback below)
    #pragma unroll
    for (int j = 0; j < 8; ++j) {
        if (bin_in[j] >= B0)  atomicAdd(&hist[bin_in[j]], 1u);
        if (bin_out[j] >= B0) atomicAdd(&hist[NBIN + bin_out[j]], 1u);
    }
    if (t == 0) {
        float oo = sred[0] + sred[2] + sred[4] + sred[6];
        float od = sred[1] + sred[3] + sred[5] + sred[7];
        float no = fmaxf(sqrtf(oo), 1e-12f);
        float nd = fmaxf(sqrtf(dd_row), 1e-12f);
        float cs = fminf(fmaxf(od / (no * nd), -1.0f), 1.0f);
        sgcos = expf(-tau * cs);
    }
    __syncthreads();                                   // B2

    scan_find(hist, wid, lane, &sBi, &sGi, &sBo, &sGo);
    __syncthreads();                                   // B3

    int Bi = sBi, Bo = sBo;
    // uniform fallback: fewer than KSEL elements above the gate -> full hist
    if (Bi < 0 || Bo < 0) {
        #pragma unroll
        for (int j = 0; j < 8; ++j) {
            if (bin_in[j] < B0)  atomicAdd(&hist[bin_in[j]], 1u);
            if (bin_out[j] < B0) atomicAdd(&hist[NBIN + bin_out[j]], 1u);
        }
        __syncthreads();
        scan_find(hist, wid, lane, &sBi, &sGi, &sBo, &sGo);
        __syncthreads();
        Bi = sBi; Bo = sBo;
    }

    int slotI[8], slotO[8];
    // gather boundary candidates; owners recompute EXACT values
    #pragma unroll
    for (int j = 0; j < 8; ++j) {
        slotI[j] = -1;
        slotO[j] = -1;
        const int ch = ((j >> 2) << 10) + t * 4 + (j & 3);
        if (bin_in[j] == Bi) {
            float xx = xr[ch];
            float ze = fabsf(__fdiv_rn(__fsub_rn(xx, ema_mean[ch]), den_in[ch]));
            int sl = atomicAdd(&sNCi, 1);
            if (sl < CAP) {
                cbI[sl] = __float_as_uint(ze);
                ciI[sl] = (uint32_t)ch;
                slotI[j] = sl;
            }
        }
        if (bin_out[j] == Bo) {
            float xx = xr[ch];
            float oe = gelu_exact(xx);
            float ze = fabsf(__fdiv_rn(__fsub_rn(oe, ema_out_mean[ch]), den_out[ch]));
            int sl = atomicAdd(&sNCo, 1);
            if (sl < CAP) {
                cbO[sl] = __float_as_uint(ze);
                ciO[sl] = (uint32_t)ch;
                slotO[j] = sl;
            }
        }
    }
    __syncthreads();                                   // B4

    // exact rank among candidates (value desc, index asc = jax tie rule)
    {
        const int nci = min(sNCi, CAP), nco = min(sNCo, CAP);
        const uint32_t needI = (uint32_t)(KSEL - sGi);
        const uint32_t needO = (uint32_t)(KSEL - sGo);
        if (t < 128) {
            for (int i = t; i < nci; i += 128) {
                uint32_t ui = cbI[i], di = ciI[i], r = 0;
                for (int jj = 0; jj < nci; ++jj) {
                    uint32_t uj = cbI[jj];
                    r += (uj > ui || (uj == ui && ciI[jj] < di)) ? 1u : 0u;
                }
                cfI[i] = (r < needI) ? 1u : 0u;
            }
        } else {
            for (int i = t - 128; i < nco; i += 128) {
                uint32_t ui = cbO[i], di = ciO[i], r = 0;
                for (int jj = 0; jj < nco; ++jj) {
                    uint32_t uj = cbO[jj];
                    r += (uj > ui || (uj == ui && ciO[jj] < di)) ? 1u : 0u;
                }
                cfO[i] = (r < needO) ? 1u : 0u;
            }
        }
    }
    __syncthreads();                                   // B5

    // epilogue: lazy gate (tanh only where selected) + write
    const float gcos = sgcos;
    #pragma unroll
    for (int g = 0; g < 2; ++g) {
        float4 r4;
        float* rp = (float*)&r4;
        #pragma unroll
        for (int l = 0; l < 4; ++l) {
            const int j = g * 4 + l;
            bool selI = (bin_in[j] > Bi) || (slotI[j] >= 0 && cfI[slotI[j]] != 0u);
            bool selO = (bin_out[j] > Bo) || (slotO[j] >= 0 && cfO[slotO[j]] != 0u);
            float gate = 1.0f;
            if (selI && selO) {
                float th = tanh_fast(gamma * zif[j]);
                gate = fminf(fmaxf(fmaf(beta, th, 1.0f), 0.1f), 8.0f);
            }
            rp[l] = ov[j] * gate * gcos;
        }
        *(float4*)(outr + (g << 10) + t * 4) = r4;
    }
}

extern "C" void kernel_launch(void* const* d_in, const int* in_sizes, int n_in,
                              void* d_out, int out_size, void* d_ws, size_t ws_size,
                              hipStream_t stream) {
    const float* x            = (const float*)d_in[0];
    const float* p_log_tau    = (const float*)d_in[2];
    const float* p_log_beta   = (const float*)d_in[3];
    const float* p_log_gamma  = (const float*)d_in[4];
    const float* ema_mean     = (const float*)d_in[5];
    const float* ema_sq       = (const float*)d_in[6];
    const float* ema_out_mean = (const float*)d_in[7];
    const float* ema_out_sq   = (const float*)d_in[8];
    const float* ema_out_dir  = (const float*)d_in[9];
    float* wsp = (float*)d_ws;
    const int rows = in_sizes[0] / D_;

    prep_kernel<<<(D_ + BLK - 1) / BLK, BLK, 0, stream>>>(
        ema_mean, ema_sq, ema_out_mean, ema_out_sq, ema_out_dir,
        p_log_tau, p_log_beta, p_log_gamma, wsp);
    gelu205_kernel<<<rows, BLK, 0, stream>>>(
        x, ema_mean, ema_out_mean, ema_out_dir, wsp,
        (float*)d_out);
}